// Round 4
// baseline (78.691 us; speedup 1.0000x reference)
//
#include <hip/hip_runtime.h>

#define NN 512
#define DD 128
#define MARGIN_F 0.3f
#define FLAG_SENTINEL 0x51C0FFEEu   // != 0xAAAAAAAA poison

// Single fused kernel. Block i:
//   1. computes distance row d[i][*] from x (L2-resident, 256 KB),
//   2. compacts positives (same label, j!=i) into an LDS list,
//   3. reduces relu(d_ij + margin - d_ik) over negatives k,
//   4. publishes one (sum, cnt) partial via device-scope atomics + flag.
// Block 0 then consumes all 512 partials (parallel flag poll, acquire) and
// writes the final scalar. No workspace init needed (flags are write-then-
// trust; sentinel != 0xAA poison). All 512 blocks co-resident -> no deadlock.
__global__ __launch_bounds__(512) void fused_triplet_kernel(
    const float* __restrict__ x,
    const int* __restrict__ labels,
    float* __restrict__ out,
    float* __restrict__ psum,
    unsigned int* __restrict__ pcnt,
    unsigned int* __restrict__ flag) {

    const int i = blockIdx.x;
    const int tid = threadIdx.x;   // one j (and one k) per thread

    __shared__ float xi[DD];
    __shared__ float ds[NN];
    __shared__ int ls[NN];
    __shared__ float tvals[NN];    // d_ij + margin for each positive j
    __shared__ int npos;
    __shared__ float wsum[8];
    __shared__ unsigned int wcnt[8];

    if (tid < DD) xi[tid] = x[i * DD + tid];
    if (tid == 0) npos = 0;
    ls[tid] = labels[tid];
    __syncthreads();

    const int li = ls[i];

    // Distance row + positive compaction (j == tid).
    {
        const float4* xj = (const float4*)(x + tid * DD);
        float acc = 0.0f;
#pragma unroll
        for (int c = 0; c < DD / 4; ++c) {
            float4 v = xj[c];
            float4 u = ((const float4*)xi)[c];   // LDS broadcast read
            float a0 = u.x - v.x;
            float a1 = u.y - v.y;
            float a2 = u.z - v.z;
            float a3 = u.w - v.w;
            acc = fmaf(a0, a0, acc);
            acc = fmaf(a1, a1, acc);
            acc = fmaf(a2, a2, acc);
            acc = fmaf(a3, a3, acc);
        }
        float dj = sqrtf(acc);
        ds[tid] = dj;
        if (ls[tid] == li && tid != i) {
            int p = atomicAdd(&npos, 1);         // LDS atomic, ~10 per block
            tvals[p] = dj + MARGIN_F;
        }
    }
    __syncthreads();

    // Triplet reduction: thread tid owns k == tid.
    const int np = npos;
    float lsum = 0.0f;
    unsigned int lcnt = 0u;
    if (ls[tid] != li) {                         // negative k (excludes k==i)
        const float dk = ds[tid];
        for (int p = 0; p < np; ++p) {
            float v = tvals[p] - dk;
            lsum += fmaxf(v, 0.0f);
            lcnt += (v > 1e-16f) ? 1u : 0u;
        }
    }

    // Wave (64) shuffle reduction, then cross-wave via LDS (8 waves).
    for (int off = 32; off > 0; off >>= 1) {
        lsum += __shfl_down(lsum, off);
        lcnt += __shfl_down(lcnt, off);
    }
    const int wave = tid >> 6;
    const int lane = tid & 63;
    if (lane == 0) { wsum[wave] = lsum; wcnt[wave] = lcnt; }
    __syncthreads();

    // Publish this block's partial (device-scope atomics bypass the
    // non-coherent per-XCD L2s), release via threadfence + flag.
    if (tid == 0) {
        float bs = 0.0f;
        unsigned int bc = 0u;
#pragma unroll
        for (int w = 0; w < 8; ++w) { bs += wsum[w]; bc += wcnt[w]; }
        atomicExch(&psum[i], bs);
        atomicExch(&pcnt[i], bc);
        __threadfence();
        atomicExch(&flag[i], FLAG_SENTINEL);
    }

    // Block 0 consumes all partials: thread tid polls flag[tid].
    if (i == 0) {
        while (atomicAdd(&flag[tid], 0u) != FLAG_SENTINEL) { }
        __threadfence();                          // acquire
        float s = atomicAdd(&psum[tid], 0.0f);    // coherent read (returns old)
        unsigned int c = atomicAdd(&pcnt[tid], 0u);
        for (int off = 32; off > 0; off >>= 1) {
            s += __shfl_down(s, off);
            c += __shfl_down(c, off);
        }
        __syncthreads();                          // reuse wsum/wcnt safely
        if (lane == 0) { wsum[wave] = s; wcnt[wave] = c; }
        __syncthreads();
        if (tid == 0) {
            float ts = 0.0f;
            unsigned int tc = 0u;
#pragma unroll
            for (int w = 0; w < 8; ++w) { ts += wsum[w]; tc += wcnt[w]; }
            out[0] = ts / ((float)tc + 1e-16f);
        }
    }
}

extern "C" void kernel_launch(void* const* d_in, const int* in_sizes, int n_in,
                              void* d_out, int out_size, void* d_ws, size_t ws_size,
                              hipStream_t stream) {
    const float* x = (const float*)d_in[0];     // [512,128] fp32
    const int* labels = (const int*)d_in[1];    // [512] int32
    float* out = (float*)d_out;                 // scalar fp32

    float* psum = (float*)d_ws;                        // 512 floats
    unsigned int* pcnt = (unsigned int*)d_ws + NN;     // 512 uints
    unsigned int* flag = (unsigned int*)d_ws + 2 * NN; // 512 uints

    fused_triplet_kernel<<<NN, 512, 0, stream>>>(x, labels, out, psum, pcnt, flag);
}

// Round 5
// 71.494 us; speedup vs baseline: 1.1007x; 1.1007x over previous
//
#include <hip/hip_runtime.h>

#define NN 512
#define DD 128
#define MARGIN_F 0.3f

// Kernel 1 (same as round-3 winner): block i computes distance row d[i][*]
// from x (L2-resident, 256 KB), compacts positives (same label, j!=i) into
// an LDS list, reduces relu(d_ij + margin - d_ik) over negatives k, writes
// one (sum,cnt) partial per block. Unconditional stores -> no ws init.
// NOTE (R4 lesson): do NOT fuse the final reduce via device-scope flag spin —
// polling coherent atomics costs ~9 us vs ~2 us for a second graph node.
__global__ __launch_bounds__(512) void triplet_partial_kernel(
    const float* __restrict__ x,
    const int* __restrict__ labels,
    float* __restrict__ psum,
    unsigned int* __restrict__ pcnt) {

    const int i = blockIdx.x;
    const int tid = threadIdx.x;   // one j (and one k) per thread

    __shared__ float xi[DD];
    __shared__ float ds[NN];
    __shared__ int ls[NN];
    __shared__ float tvals[NN];    // d_ij + margin for each positive j
    __shared__ int npos;
    __shared__ float wsum[8];
    __shared__ unsigned int wcnt[8];

    if (tid < DD) xi[tid] = x[i * DD + tid];
    if (tid == 0) npos = 0;
    ls[tid] = labels[tid];
    __syncthreads();

    const int li = ls[i];

    // Distance row + positive compaction (j == tid).
    {
        const float4* xj = (const float4*)(x + tid * DD);
        float acc = 0.0f;
#pragma unroll
        for (int c = 0; c < DD / 4; ++c) {
            float4 v = xj[c];
            float4 u = ((const float4*)xi)[c];   // LDS broadcast read
            float a0 = u.x - v.x;
            float a1 = u.y - v.y;
            float a2 = u.z - v.z;
            float a3 = u.w - v.w;
            acc = fmaf(a0, a0, acc);
            acc = fmaf(a1, a1, acc);
            acc = fmaf(a2, a2, acc);
            acc = fmaf(a3, a3, acc);
        }
        float dj = sqrtf(acc);
        ds[tid] = dj;
        if (ls[tid] == li && tid != i) {
            int p = atomicAdd(&npos, 1);         // LDS atomic, ~10 per block
            tvals[p] = dj + MARGIN_F;
        }
    }
    __syncthreads();

    // Triplet reduction: thread tid owns k == tid.
    const int np = npos;
    float lsum = 0.0f;
    unsigned int lcnt = 0u;
    if (ls[tid] != li) {                         // negative k (excludes k==i)
        const float dk = ds[tid];
        for (int p = 0; p < np; ++p) {
            float v = tvals[p] - dk;
            lsum += fmaxf(v, 0.0f);
            lcnt += (v > 1e-16f) ? 1u : 0u;
        }
    }

    // Wave (64) shuffle reduction, then cross-wave via LDS (8 waves).
    for (int off = 32; off > 0; off >>= 1) {
        lsum += __shfl_down(lsum, off);
        lcnt += __shfl_down(lcnt, off);
    }
    const int wave = tid >> 6;
    const int lane = tid & 63;
    if (lane == 0) { wsum[wave] = lsum; wcnt[wave] = lcnt; }
    __syncthreads();

    if (tid == 0) {
        float bs = 0.0f;
        unsigned int bc = 0u;
#pragma unroll
        for (int w = 0; w < 8; ++w) { bs += wsum[w]; bc += wcnt[w]; }
        psum[i] = bs;                            // plain stores, slot per block
        pcnt[i] = bc;
    }
}

// Kernel 2: reduce 512 partials -> scalar. ONE wave (64 threads): no LDS,
// no __syncthreads, serial 8-partial accumulate + shuffle tree. Kernel
// boundary gives cross-XCD visibility of kernel-1 stores (R3 verified).
__global__ __launch_bounds__(64) void reduce_kernel(
    const float* __restrict__ psum,
    const unsigned int* __restrict__ pcnt,
    float* __restrict__ out) {

    const int tid = threadIdx.x;
    float lsum = 0.0f;
    unsigned int lcnt = 0u;
#pragma unroll
    for (int w = 0; w < NN / 64; ++w) {
        lsum += psum[w * 64 + tid];
        lcnt += pcnt[w * 64 + tid];
    }
    for (int off = 32; off > 0; off >>= 1) {
        lsum += __shfl_down(lsum, off);
        lcnt += __shfl_down(lcnt, off);
    }
    if (tid == 0) out[0] = lsum / ((float)lcnt + 1e-16f);
}

extern "C" void kernel_launch(void* const* d_in, const int* in_sizes, int n_in,
                              void* d_out, int out_size, void* d_ws, size_t ws_size,
                              hipStream_t stream) {
    const float* x = (const float*)d_in[0];     // [512,128] fp32
    const int* labels = (const int*)d_in[1];    // [512] int32
    float* out = (float*)d_out;                 // scalar fp32

    float* psum = (float*)d_ws;                     // 512 floats
    unsigned int* pcnt = (unsigned int*)d_ws + NN;  // 512 uints

    triplet_partial_kernel<<<NN, 512, 0, stream>>>(x, labels, psum, pcnt);
    reduce_kernel<<<1, 64, 0, stream>>>(psum, pcnt, out);
}